// Round 11
// baseline (92.064 us; speedup 1.0000x reference)
//
#include <hip/hip_runtime.h>

typedef unsigned int uint;
typedef unsigned short ushort;
typedef __attribute__((ext_vector_type(8))) short short8;
typedef __attribute__((ext_vector_type(4))) float f32x4;

#define B_   512
#define V_   256
#define M_   128
#define H_   512
#define T_   16
#define KTOT 34816   // V_*M_ + M_*T_

// ---------------- helpers ----------------
__device__ __forceinline__ ushort f2bf(float f) {
  uint u = __builtin_bit_cast(uint, f);
  u += 0x7fffu + ((u >> 16) & 1u);   // RNE
  return (ushort)(u >> 16);
}
__device__ __forceinline__ float bf2f(ushort s) {
  return __builtin_bit_cast(float, ((uint)s) << 16);
}

// sigma-swizzle: within each 32-element (64B) k-group, XOR the 16B-chunk index
// with ((row>>1)&3). A's writer (prep) applies it; gemm1 reads it back.
__device__ __forceinline__ int swz_k(int k, int row) {
  return (k & ~31) | (((((k >> 3) & 3) ^ ((row >> 1) & 3)) << 3)) | (k & 7);
}

// ---------------- kernel 1: per-batch prep ----------------
__global__ __launch_bounds__(256) void prep_kernel(
    const float* __restrict__ x, const float* __restrict__ mem,
    const int* __restrict__ timings, const float* __restrict__ msurp,
    const float* __restrict__ b1,
    ushort* __restrict__ A, float* __restrict__ h_pre)
{
  const int b = blockIdx.x, tid = threadIdx.x;
  __shared__ int s_t[M_];
  __shared__ int s_row[M_];
  __shared__ int s_st[M_];
  __shared__ int s_idx;

  if (tid < 64) {
    float v0 = msurp[b * M_ + tid];
    float v1 = msurp[b * M_ + tid + 64];
    float v; int i;
    if (v1 < v0) { v = v1; i = tid + 64; } else { v = v0; i = tid; }
    #pragma unroll
    for (int off = 32; off > 0; off >>= 1) {
      float ov = __shfl_down(v, off);
      int   oi = __shfl_down(i, off);
      if (ov < v || (ov == v && oi < i)) { v = ov; i = oi; }
    }
    if (tid == 0) s_idx = i;
  }
  __syncthreads();
  const int idx = s_idx;

  if (tid < M_) {
    int t = timings[b * M_ + tid] + 1;
    if (tid == idx) t = 0;
    s_t[tid] = t;
  }
  h_pre[(size_t)b * H_ + tid]       = b1[tid];
  h_pre[(size_t)b * H_ + 256 + tid] = b1[256 + tid];
  __syncthreads();

  if (tid < M_) {
    const int t = s_t[tid];
    int r = 0;
    for (int j = 0; j < M_; ++j) {
      int tj = s_t[j];
      r += (tj < t || (tj == t && j < tid)) ? 1 : 0;
    }
    s_row[r] = tid;   // order[r] = tid
    s_st[r]  = t;     // sorted_t[r]
  }
  __syncthreads();

  // bits region (k >= 32768), swizzled writes
  if (tid < M_) {
    const int t = s_st[tid];
    uint p[8];
    #pragma unroll
    for (int h = 0; h < 8; ++h) {
      uint lo = ((t >> (2 * h)) & 1) ? 0x3F80u : 0u;
      uint hi = ((t >> (2 * h + 1)) & 1) ? 0x3F80u : 0u;
      p[h] = lo | (hi << 16);
    }
    const int k0 = V_ * M_ + tid * T_;
    uint4 w0; w0.x = p[0]; w0.y = p[1]; w0.z = p[2]; w0.w = p[3];
    uint4 w1; w1.x = p[4]; w1.y = p[5]; w1.z = p[6]; w1.w = p[7];
    *(uint4*)(A + (size_t)b * KTOT + swz_k(k0, b))     = w0;
    *(uint4*)(A + (size_t)b * KTOT + swz_k(k0 + 8, b)) = w1;
  }

  // gather rows, swizzled writes (8B pieces stay within one 16B chunk)
  const int lane = tid & 63, sub = tid >> 6;
  for (int it = 0; it < 32; ++it) {
    const int slot = it * 4 + sub;
    const int rowm = s_row[slot];
    const float* src = (rowm == idx) ? (x + (size_t)b * V_)
                                     : (mem + ((size_t)b * M_ + rowm) * V_);
    f32x4 v = *(const f32x4*)(src + lane * 4);
    uint2 o;
    o.x = (uint)f2bf(v[0]) | ((uint)f2bf(v[1]) << 16);
    o.y = (uint)f2bf(v[2]) | ((uint)f2bf(v[3]) << 16);
    const int k = slot * V_ + lane * 4;
    *(uint2*)(A + (size_t)b * KTOT + swz_k(k, b)) = o;
  }
}

// ---------------- kernel 2: split-K bf16 MFMA GEMM, 512x128, BK=64 ----------------
// Barrier-count experiment: 8 x 64-k iterations + 1 x 32-k tail = ~10 barriers
// (vs 17). Same bytes, same VMEM op count, same MFMA count as the BK=32 version.
// A: global_load_lds (wave-private rows), 2 x 64KB buffers.
// B: reg-stage f32 W1 -> bf16 -> swizzled ds_write, 2 x 16KB buffers.
// Per-iter/wave VMEM = 8 gld_lds + 16 loadB dwords; entry vmcnt(16) steady.
#define BM 512
#define BN 128
#define SPLITK 64
#define KCH 544
#define NFULL 8     // 8 x 64-k, then 32-k tail

#define GLD16(g, l) __builtin_amdgcn_global_load_lds( \
  (const __attribute__((address_space(1))) void*)(g), \
  (__attribute__((address_space(3))) void*)(l), 16, 0, 0)

template<bool USE_ATOMIC>
__global__ __launch_bounds__(512, 2) void gemm1_kernel(
    const ushort* __restrict__ A, const float* __restrict__ W1,
    void* __restrict__ dstv)   // fp32 h_pre (atomic) or bf16 partials P[SPLITK][512][512]
{
  __shared__ __align__(16) ushort As[2][BM * 64];   // 128 KB
  __shared__ __align__(16) ushort Bs[2][BN * 64];   // 32 KB  (total 160 KB exact)

  const int bid  = blockIdx.x;
  const int sk   = (bid & 7) | ((bid >> 5) << 3);   // 0..63 (same-sk quads share XCD)
  const int tile = (bid >> 3) & 3;                  // 4 n-tiles
  const int n0   = tile * BN;
  const int tid  = threadIdx.x, wave = tid >> 6, lane = tid & 63;
  const long kb0 = (long)sk * KCH;

  f32x4 acc[4][8];
  #pragma unroll
  for (int i = 0; i < 4; ++i)
    #pragma unroll
    for (int j = 0; j < 8; ++j) acc[i][j] = (f32x4)0.f;

  // ---- A staging, full 64-k chunk: 8 gld_lds/wave, rows wave*64..+64 (wave-private)
  const int ar8  = wave * 64 + (lane >> 3);
  const int akk8 = (lane & 7) * 8;
  auto stageA64 = [&](int buf, int c) {
    const long kb = kb0 + (long)c * 64;
    #pragma unroll
    for (int q = 0; q < 8; ++q)
      GLD16(A + ((size_t)(ar8 + q * 8)) * KTOT + kb + akk8,
            &As[buf][(wave * 64 + q * 8) * 64]);
  };
  // ---- A staging, 32-k tail into As[0] viewed as [512][32]
  const int ar4  = wave * 64 + (lane >> 2);
  const int akk4 = (lane & 3) * 8;
  auto stageA32 = [&]() {
    const long kb = kb0 + 512;
    #pragma unroll
    for (int q = 0; q < 4; ++q)
      GLD16(A + ((size_t)(ar4 + q * 16)) * KTOT + kb + akk4,
            &As[0][(wave * 64 + q * 16) * 32]);
  };

  // ---- B staging: thread -> col n0+(tid&127), 16 k's (full) / 8 k's (tail)
  const int ncol = tid & 127;
  const int koct = tid >> 7;                  // 0..3
  const int sg   = (ncol >> 1) & 3;
  const float* w1p  = W1 + (size_t)(kb0 + koct * 16) * H_ + n0 + ncol;
  const float* w1pt = W1 + (size_t)(kb0 + 512 + koct * 8) * H_ + n0 + ncol;
  const int g64 = (koct >> 1), c064 = (koct & 1) * 2;
  const int bw0 = ncol * 64 + g64 * 32 + ((c064 ^ sg) * 8);
  const int bw1 = ncol * 64 + g64 * 32 + (((c064 + 1) ^ sg) * 8);
  const int bwt = ncol * 32 + ((koct ^ sg) * 8);

  auto loadB64 = [&](float* r, int c) {
    const float* p = w1p + (size_t)c * 64 * H_;
    #pragma unroll
    for (int i = 0; i < 16; ++i) r[i] = p[(size_t)i * H_];
  };
  auto writeB64 = [&](const float* r, ushort* base) {
    uint4 o0, o1;
    o0.x = (uint)f2bf(r[0])  | ((uint)f2bf(r[1])  << 16);
    o0.y = (uint)f2bf(r[2])  | ((uint)f2bf(r[3])  << 16);
    o0.z = (uint)f2bf(r[4])  | ((uint)f2bf(r[5])  << 16);
    o0.w = (uint)f2bf(r[6])  | ((uint)f2bf(r[7])  << 16);
    o1.x = (uint)f2bf(r[8])  | ((uint)f2bf(r[9])  << 16);
    o1.y = (uint)f2bf(r[10]) | ((uint)f2bf(r[11]) << 16);
    o1.z = (uint)f2bf(r[12]) | ((uint)f2bf(r[13]) << 16);
    o1.w = (uint)f2bf(r[14]) | ((uint)f2bf(r[15]) << 16);
    *(uint4*)(base + bw0) = o0;
    *(uint4*)(base + bw1) = o1;
  };
  auto loadB32 = [&](float* r) {
    #pragma unroll
    for (int i = 0; i < 8; ++i) r[i] = w1pt[(size_t)i * H_];
  };
  auto writeB32 = [&](const float* r, ushort* base) {
    uint4 o;
    o.x = (uint)f2bf(r[0]) | ((uint)f2bf(r[1]) << 16);
    o.y = (uint)f2bf(r[2]) | ((uint)f2bf(r[3]) << 16);
    o.z = (uint)f2bf(r[4]) | ((uint)f2bf(r[5]) << 16);
    o.w = (uint)f2bf(r[6]) | ((uint)f2bf(r[7]) << 16);
    *(uint4*)(base + bwt) = o;
  };

  // frag-read addressing (de-swizzle within 32-groups, per 64B half-row)
  const int xo    = (((lane >> 4) ^ ((lane >> 1) & 3)) * 8);
  const int a_ro  = (wave * 64 + (lane & 15)) * 64;
  const int b_ro  = (lane & 15) * 64;

  float brE[16], brO[16], brT[8];

#define FITER(C, BRL, BRW, ISSA, ISSB, ISSBT, ISSAT, W64, W32, VMC) do {      \
    asm volatile("s_waitcnt vmcnt(" VMC ") lgkmcnt(0)" ::: "memory");         \
    __builtin_amdgcn_s_barrier();                                             \
    __builtin_amdgcn_sched_barrier(0);                                        \
    if (ISSA)  stageA64(((C) + 1) & 1, (C) + 1);                              \
    if (ISSB)  loadB64(BRL, (C) + 2);                                         \
    if (ISSBT) loadB32(brT);                                                  \
    if (ISSAT) stageA32();                                                    \
    _Pragma("unroll") for (int h = 0; h < 2; ++h) {                           \
      const ushort* as_ = &As[(C) & 1][a_ro + h * 32 + xo];                   \
      const ushort* bs_ = &Bs[(C) & 1][b_ro + h * 32 + xo];                   \
      short8 af[4], bf[4];                                                    \
      _Pragma("unroll") for (int i = 0; i < 4; ++i)                           \
        af[i] = *(const short8*)(as_ + i * 16 * 64);                          \
      _Pragma("unroll") for (int j = 0; j < 4; ++j)                           \
        bf[j] = *(const short8*)(bs_ + j * 16 * 64);                          \
      _Pragma("unroll") for (int i = 0; i < 4; ++i)                           \
        _Pragma("unroll") for (int j = 0; j < 4; ++j)                         \
          acc[i][j] = __builtin_amdgcn_mfma_f32_16x16x32_bf16(af[i], bf[j],   \
                                                          acc[i][j], 0,0,0);  \
      _Pragma("unroll") for (int j = 0; j < 4; ++j)                           \
        bf[j] = *(const short8*)(bs_ + (j + 4) * 16 * 64);                    \
      _Pragma("unroll") for (int i = 0; i < 4; ++i)                           \
        _Pragma("unroll") for (int j = 0; j < 4; ++j)                         \
          acc[i][j + 4] = __builtin_amdgcn_mfma_f32_16x16x32_bf16(af[i],      \
                                               bf[j], acc[i][j + 4], 0,0,0);  \
    }                                                                         \
    if (W64) writeB64(BRW, &Bs[((C) + 1) & 1][0]);                            \
    if (W32) writeB32(brT, &Bs[0][0]);                                        \
  } while (0)

  // prologue: A(0) staged; B(0),B(1) in regs; Bs[0] = chunk 0
  loadB64(brE, 0);
  stageA64(0, 0);
  loadB64(brO, 1);
  writeB64(brE, &Bs[0][0]);

  FITER(0, brE, brO, true,  true,  false, false, true,  false, "16");
  FITER(1, brO, brE, true,  true,  false, false, true,  false, "16");
  FITER(2, brE, brO, true,  true,  false, false, true,  false, "16");
  FITER(3, brO, brE, true,  true,  false, false, true,  false, "16");
  FITER(4, brE, brO, true,  true,  false, false, true,  false, "16");
  FITER(5, brO, brE, true,  true,  false, false, true,  false, "16");
  FITER(6, brE, brO, true,  false, true,  false, true,  false, "16");
  FITER(7, brO, brE, false, false, false, true,  false, true,  "8");
#undef FITER

  // ---- 32-k tail: As[0]/Bs[0] in [.][32] layout
  {
    asm volatile("s_waitcnt vmcnt(0) lgkmcnt(0)" ::: "memory");
    __builtin_amdgcn_s_barrier();
    __builtin_amdgcn_sched_barrier(0);
    const ushort* as_ = &As[0][(wave * 64 + (lane & 15)) * 32 + xo];
    const ushort* bs_ = &Bs[0][(lane & 15) * 32 + xo];
    short8 af[4], bf[4];
    #pragma unroll
    for (int i = 0; i < 4; ++i)
      af[i] = *(const short8*)(as_ + i * 16 * 32);
    #pragma unroll
    for (int j = 0; j < 4; ++j)
      bf[j] = *(const short8*)(bs_ + j * 16 * 32);
    #pragma unroll
    for (int i = 0; i < 4; ++i)
      #pragma unroll
      for (int j = 0; j < 4; ++j)
        acc[i][j] = __builtin_amdgcn_mfma_f32_16x16x32_bf16(af[i], bf[j], acc[i][j], 0, 0, 0);
    #pragma unroll
    for (int j = 0; j < 4; ++j)
      bf[j] = *(const short8*)(bs_ + (j + 4) * 16 * 32);
    #pragma unroll
    for (int i = 0; i < 4; ++i)
      #pragma unroll
      for (int j = 0; j < 4; ++j)
        acc[i][j + 4] = __builtin_amdgcn_mfma_f32_16x16x32_bf16(af[i], bf[j], acc[i][j + 4], 0, 0, 0);
  }

  const int row0 = wave * 64 + (lane >> 4) * 4;
  const int col0 = n0 + (lane & 15);
  if constexpr (USE_ATOMIC) {
    float* dst = (float*)dstv;
    #pragma unroll
    for (int i = 0; i < 4; ++i)
      #pragma unroll
      for (int j = 0; j < 8; ++j)
        #pragma unroll
        for (int r = 0; r < 4; ++r)
          atomicAdd(&dst[(size_t)(row0 + i * 16 + r) * H_ + col0 + j * 16], acc[i][j][r]);
  } else {
    ushort* P = (ushort*)dstv + (size_t)sk * (B_ * H_);
    #pragma unroll
    for (int i = 0; i < 4; ++i)
      #pragma unroll
      for (int j = 0; j < 8; ++j)
        #pragma unroll
        for (int r = 0; r < 4; ++r)
          P[(size_t)(row0 + i * 16 + r) * H_ + col0 + j * 16] = f2bf(acc[i][j][r]);
  }
}

// ---------------- kernel 3: fused reduce + relu + GEMM2 ----------------
template<bool FROM_PARTIALS>
__global__ __launch_bounds__(256) void gemm2_kernel(
    const void* __restrict__ Pin, const float* __restrict__ b1,
    const float* __restrict__ W2, const float* __restrict__ b2,
    float* __restrict__ out)
{
  const int bb = blockIdx.x * 2;   // 256 blocks, 2 batch rows each
  const int v  = threadIdx.x;      // 0..255
  __shared__ float hs[2][H_];

  {
    const int id  = v * 4;
    const int row = id >> 9, col = id & 511;
    f32x4 s;
    if constexpr (FROM_PARTIALS) {
      const ushort* P = (const ushort*)Pin;
      s = *(const f32x4*)(b1 + col);
      #pragma unroll 4
      for (int sk = 0; sk < SPLITK; ++sk) {
        uint2 u = *(const uint2*)(P + (size_t)sk * (B_ * H_) + (size_t)(bb + row) * H_ + col);
        s[0] += bf2f((ushort)(u.x & 0xffff));
        s[1] += bf2f((ushort)(u.x >> 16));
        s[2] += bf2f((ushort)(u.y & 0xffff));
        s[3] += bf2f((ushort)(u.y >> 16));
      }
    } else {
      s = *(const f32x4*)((const float*)Pin + (size_t)(bb + row) * H_ + col);
    }
    f32x4 r;
    #pragma unroll
    for (int t = 0; t < 4; ++t) r[t] = fmaxf(s[t], 0.f);
    *(f32x4*)&hs[row][col] = r;
  }
  __syncthreads();

  float a0 = 0.f, a1 = 0.f;
  for (int j4 = 0; j4 < H_ / 4; ++j4) {
    f32x4 h0 = *(const f32x4*)&hs[0][j4 * 4];
    f32x4 h1 = *(const f32x4*)&hs[1][j4 * 4];
    #pragma unroll
    for (int t = 0; t < 4; ++t) {
      float w = W2[(size_t)(j4 * 4 + t) * V_ + v];
      a0 += h0[t] * w; a1 += h1[t] * w;
    }
  }
  const float bias = b2[v];
  out[(size_t)(bb + 0) * V_ + v] = a0 + bias;
  out[(size_t)(bb + 1) * V_ + v] = a1 + bias;
}

// ---------------- launch ----------------
extern "C" void kernel_launch(void* const* d_in, const int* in_sizes, int n_in,
                              void* d_out, int out_size, void* d_ws, size_t ws_size,
                              hipStream_t stream) {
  const float* x   = (const float*)d_in[0];
  const float* mem = (const float*)d_in[1];
  const int*   tim = (const int*)d_in[2];
  const float* msu = (const float*)d_in[3];
  const float* W1  = (const float*)d_in[5];
  const float* b1  = (const float*)d_in[6];
  const float* W2  = (const float*)d_in[7];
  const float* b2  = (const float*)d_in[8];
  float* out = (float*)d_out;

  char* ws = (char*)d_ws;
  const size_t abytes = (size_t)B_ * KTOT * 2;          // 35,651,584
  const size_t pbytes = (size_t)SPLITK * B_ * H_ * 2;   // 33,554,432 (bf16 partials)
  const size_t hbytes = (size_t)B_ * H_ * 4;            // 1,048,576
  const bool partials = ws_size >= abytes + pbytes + hbytes;

  ushort* A_ws  = (ushort*)ws;
  void*   P     = (void*)(ws + abytes);
  float*  h_pre = partials ? (float*)(ws + abytes + pbytes)
                           : (float*)(ws + abytes);

  prep_kernel<<<B_, 256, 0, stream>>>(x, mem, tim, msu, b1, A_ws, h_pre);
  if (partials) {
    gemm1_kernel<false><<<4 * SPLITK, 512, 0, stream>>>(A_ws, W1, P);
    gemm2_kernel<true><<<B_ / 2, 256, 0, stream>>>(P, b1, W2, b2, out);
  } else {
    gemm1_kernel<true><<<4 * SPLITK, 512, 0, stream>>>(A_ws, W1, h_pre);
    gemm2_kernel<false><<<B_ / 2, 256, 0, stream>>>(h_pre, b1, W2, b2, out);
  }
}

// Round 12
// 77.852 us; speedup vs baseline: 1.1825x; 1.1825x over previous
//
#include <hip/hip_runtime.h>

typedef unsigned int uint;
typedef unsigned short ushort;
typedef __attribute__((ext_vector_type(8))) short short8;
typedef __attribute__((ext_vector_type(4))) float f32x4;

#define B_   512
#define V_   256
#define M_   128
#define H_   512
#define T_   16
#define KTOT 34816   // V_*M_ + M_*T_

// ---------------- helpers ----------------
__device__ __forceinline__ ushort f2bf(float f) {
  uint u = __builtin_bit_cast(uint, f);
  u += 0x7fffu + ((u >> 16) & 1u);   // RNE
  return (ushort)(u >> 16);
}
__device__ __forceinline__ float bf2f(ushort s) {
  return __builtin_bit_cast(float, ((uint)s) << 16);
}

// sigma-swizzle: within each 32-element (64B) k-group, XOR the 16B-chunk index
// with ((row>>1)&3). A's writer (prep) applies it; gemm1 reads it back.
__device__ __forceinline__ int swz_k(int k, int row) {
  return (k & ~31) | (((((k >> 3) & 3) ^ ((row >> 1) & 3)) << 3)) | (k & 7);
}

// ---------------- kernel 1: per-batch prep ----------------
__global__ __launch_bounds__(256) void prep_kernel(
    const float* __restrict__ x, const float* __restrict__ mem,
    const int* __restrict__ timings, const float* __restrict__ msurp,
    const float* __restrict__ b1,
    ushort* __restrict__ A, float* __restrict__ h_pre)
{
  const int b = blockIdx.x, tid = threadIdx.x;
  __shared__ int s_t[M_];
  __shared__ int s_row[M_];
  __shared__ int s_st[M_];
  __shared__ int s_idx;

  if (tid < 64) {
    float v0 = msurp[b * M_ + tid];
    float v1 = msurp[b * M_ + tid + 64];
    float v; int i;
    if (v1 < v0) { v = v1; i = tid + 64; } else { v = v0; i = tid; }
    #pragma unroll
    for (int off = 32; off > 0; off >>= 1) {
      float ov = __shfl_down(v, off);
      int   oi = __shfl_down(i, off);
      if (ov < v || (ov == v && oi < i)) { v = ov; i = oi; }
    }
    if (tid == 0) s_idx = i;
  }
  __syncthreads();
  const int idx = s_idx;

  if (tid < M_) {
    int t = timings[b * M_ + tid] + 1;
    if (tid == idx) t = 0;
    s_t[tid] = t;
  }
  h_pre[(size_t)b * H_ + tid]       = b1[tid];
  h_pre[(size_t)b * H_ + 256 + tid] = b1[256 + tid];
  __syncthreads();

  if (tid < M_) {
    const int t = s_t[tid];
    int r = 0;
    for (int j = 0; j < M_; ++j) {
      int tj = s_t[j];
      r += (tj < t || (tj == t && j < tid)) ? 1 : 0;
    }
    s_row[r] = tid;   // order[r] = tid
    s_st[r]  = t;     // sorted_t[r]
  }
  __syncthreads();

  // bits region (k >= 32768), swizzled writes
  if (tid < M_) {
    const int t = s_st[tid];
    uint p[8];
    #pragma unroll
    for (int h = 0; h < 8; ++h) {
      uint lo = ((t >> (2 * h)) & 1) ? 0x3F80u : 0u;
      uint hi = ((t >> (2 * h + 1)) & 1) ? 0x3F80u : 0u;
      p[h] = lo | (hi << 16);
    }
    const int k0 = V_ * M_ + tid * T_;
    uint4 w0; w0.x = p[0]; w0.y = p[1]; w0.z = p[2]; w0.w = p[3];
    uint4 w1; w1.x = p[4]; w1.y = p[5]; w1.z = p[6]; w1.w = p[7];
    *(uint4*)(A + (size_t)b * KTOT + swz_k(k0, b))     = w0;
    *(uint4*)(A + (size_t)b * KTOT + swz_k(k0 + 8, b)) = w1;
  }

  // gather rows, swizzled writes (8B pieces stay within one 16B chunk)
  const int lane = tid & 63, sub = tid >> 6;
  for (int it = 0; it < 32; ++it) {
    const int slot = it * 4 + sub;
    const int rowm = s_row[slot];
    const float* src = (rowm == idx) ? (x + (size_t)b * V_)
                                     : (mem + ((size_t)b * M_ + rowm) * V_);
    f32x4 v = *(const f32x4*)(src + lane * 4);
    uint2 o;
    o.x = (uint)f2bf(v[0]) | ((uint)f2bf(v[1]) << 16);
    o.y = (uint)f2bf(v[2]) | ((uint)f2bf(v[3]) << 16);
    const int k = slot * V_ + lane * 4;
    *(uint2*)(A + (size_t)b * KTOT + swz_k(k, b)) = o;
  }
}

// ---------------- kernel 2: split-K bf16 MFMA GEMM, 512x128 tile, BK=32 ----------------
// R9 structure (proven best: 42us, 0 bank conflicts) + T5 s_setprio around the
// ds_read+MFMA region. Depth-3 B register pipeline, 3 LDS A-buffers, counted
// vmcnt(20); never drains in steady state.
#define BM 512
#define BN 128
#define SPLITK 64
#define KCH 544
#define NCHU 17

#define GLD16(g, l) __builtin_amdgcn_global_load_lds( \
  (const __attribute__((address_space(1))) void*)(g), \
  (__attribute__((address_space(3))) void*)(l), 16, 0, 0)

template<bool USE_ATOMIC>
__global__ __launch_bounds__(512, 2) void gemm1_kernel(
    const ushort* __restrict__ A, const float* __restrict__ W1,
    void* __restrict__ dstv)   // fp32 h_pre (atomic) or bf16 partials P[SPLITK][512][512]
{
  __shared__ __align__(16) ushort As[3][BM * 32];   // 96 KB
  __shared__ __align__(16) ushort Bs[2][BN * 32];   // 16 KB

  const int bid  = blockIdx.x;
  // XCD-aligned: same-sk blocks share bid%8 -> same XCD (grid 256 = 4 n-tiles x 64 sk)
  const int sk   = (bid & 7) | ((bid >> 5) << 3);   // 0..63
  const int tile = (bid >> 3) & 3;                  // 4 n-tiles
  const int n0   = tile * BN;
  const int tid  = threadIdx.x, wave = tid >> 6, lane = tid & 63;
  const long kb0 = (long)sk * KCH;

  f32x4 acc[4][8];
  #pragma unroll
  for (int i = 0; i < 4; ++i)
    #pragma unroll
    for (int j = 0; j < 8; ++j) acc[i][j] = (f32x4)0.f;

  // A staging (global_load_lds, linear dest): each wave owns rows [wave*64, wave*64+64)
  const int ar  = wave * 64 + (lane >> 2);
  const int akk = (lane & 3) * 8;
  auto stageA = [&](int buf, int chunk) {
    const long kb = kb0 + (long)chunk * 32;
    #pragma unroll
    for (int q = 0; q < 4; ++q)
      GLD16(A + ((size_t)(ar + q * 16)) * KTOT + kb + akk,
            &As[buf][(wave * 64 + q * 16) * 32]);
  };

  // B staging: thread -> column n = n0+(tid&127), k-octet koct = tid>>7 (8 k's)
  const int ncol = tid & 127;
  const int koct = tid >> 7;                 // 0..3
  const float* w1p = W1 + (size_t)(kb0 + koct * 8) * H_ + n0 + ncol;
  const int b_woff = ncol * 32 + ((koct ^ ((ncol >> 1) & 3)) * 8);

  auto loadB = [&](float* r, int c) {
    const float* p = w1p + (size_t)c * 32 * H_;
    #pragma unroll
    for (int i = 0; i < 8; ++i) r[i] = p[(size_t)i * H_];
  };
  auto writeB = [&](const float* r, ushort* base) {
    uint4 o;
    o.x = (uint)f2bf(r[0]) | ((uint)f2bf(r[1]) << 16);
    o.y = (uint)f2bf(r[2]) | ((uint)f2bf(r[3]) << 16);
    o.z = (uint)f2bf(r[4]) | ((uint)f2bf(r[5]) << 16);
    o.w = (uint)f2bf(r[6]) | ((uint)f2bf(r[7]) << 16);
    *(uint4*)(base + b_woff) = o;
  };

  // de-swizzle read offset for frag loads
  const int xo     = (((lane >> 4) ^ ((lane >> 1) & 3)) * 8);
  const int a_roff = (wave * 64 + (lane & 15)) * 32;
  const int b_roff = (lane & 15) * 32;

  float brA[8], brB[8], brC[8];

// C: runtime chunk index; A3 = C%3, AS2 = (C+2)%3, CPAR = C&1 (all static);
// BRL = br[C%3] (load target, chunk C+3); BRW = br[(C+1)%3] (write source, chunk C+1)
#define GITER(C, A3, AS2, CPAR, BRL, BRW, ISSA, ISSB, WRITE, VMC) do {        \
    asm volatile("s_waitcnt vmcnt(" VMC ") lgkmcnt(0)" ::: "memory");         \
    __builtin_amdgcn_s_barrier();                                             \
    __builtin_amdgcn_sched_barrier(0);                                        \
    if (ISSA) stageA(AS2, (C) + 2);                                           \
    if (ISSB) loadB(BRL, (C) + 3);                                            \
    __builtin_amdgcn_s_setprio(1);                                            \
    const ushort* as_ = &As[A3][a_roff + xo];                                 \
    const ushort* bs_ = &Bs[CPAR][b_roff + xo];                               \
    short8 af[4], bf[4];                                                      \
    _Pragma("unroll") for (int i = 0; i < 4; ++i)                             \
      af[i] = *(const short8*)(as_ + i * 16 * 32);                            \
    _Pragma("unroll") for (int j = 0; j < 4; ++j)                             \
      bf[j] = *(const short8*)(bs_ + j * 16 * 32);                            \
    _Pragma("unroll") for (int i = 0; i < 4; ++i)                             \
      _Pragma("unroll") for (int j = 0; j < 4; ++j)                           \
        acc[i][j] = __builtin_amdgcn_mfma_f32_16x16x32_bf16(af[i], bf[j],     \
                                                            acc[i][j], 0,0,0);\
    _Pragma("unroll") for (int j = 0; j < 4; ++j)                             \
      bf[j] = *(const short8*)(bs_ + (j + 4) * 16 * 32);                      \
    _Pragma("unroll") for (int i = 0; i < 4; ++i)                             \
      _Pragma("unroll") for (int j = 0; j < 4; ++j)                           \
        acc[i][j + 4] = __builtin_amdgcn_mfma_f32_16x16x32_bf16(af[i], bf[j], \
                                                            acc[i][j + 4],    \
                                                            0, 0, 0);         \
    __builtin_amdgcn_s_setprio(0);                                            \
    if (WRITE) writeB(BRW, &Bs[(CPAR) ^ 1][0]);                               \
  } while (0)

  // prologue: chunks 0,1 staged (A); chunks 0,1,2 loaded (B regs); Bs[0] = chunk 0
  loadB(brA, 0);
  stageA(0, 0);
  loadB(brB, 1);
  stageA(1, 1);
  loadB(brC, 2);
  writeB(brA, &Bs[0][0]);

  #pragma unroll 1
  for (int cc = 0; cc < 12; cc += 6) {
    GITER(cc + 0, 0, 2, 0, brA, brB, true, true, true, "20");
    GITER(cc + 1, 1, 0, 1, brB, brC, true, true, true, "20");
    GITER(cc + 2, 2, 1, 0, brC, brA, true, true, true, "20");
    GITER(cc + 3, 0, 2, 1, brA, brB, true, true, true, "20");
    GITER(cc + 4, 1, 0, 0, brB, brC, true, true, true, "20");
    GITER(cc + 5, 2, 1, 1, brC, brA, true, true, true, "20");
  }
  GITER(12, 0, 2, 0, brA, brB, true,  true,  true,  "20");
  GITER(13, 1, 0, 1, brB, brC, true,  true,  true,  "20");
  GITER(14, 2, 1, 0, brC, brA, true,  false, true,  "20");
  GITER(15, 0, 2, 1, brA, brB, false, false, true,  "12");
  GITER(16, 1, 0, 0, brB, brC, false, false, false, "0");
#undef GITER

  const int row0 = wave * 64 + (lane >> 4) * 4;
  const int col0 = n0 + (lane & 15);
  if constexpr (USE_ATOMIC) {
    float* dst = (float*)dstv;
    #pragma unroll
    for (int i = 0; i < 4; ++i)
      #pragma unroll
      for (int j = 0; j < 8; ++j)
        #pragma unroll
        for (int r = 0; r < 4; ++r)
          atomicAdd(&dst[(size_t)(row0 + i * 16 + r) * H_ + col0 + j * 16], acc[i][j][r]);
  } else {
    ushort* P = (ushort*)dstv + (size_t)sk * (B_ * H_);
    #pragma unroll
    for (int i = 0; i < 4; ++i)
      #pragma unroll
      for (int j = 0; j < 8; ++j)
        #pragma unroll
        for (int r = 0; r < 4; ++r)
          P[(size_t)(row0 + i * 16 + r) * H_ + col0 + j * 16] = f2bf(acc[i][j][r]);
  }
}

// ---------------- kernel 3: fused reduce + relu + GEMM2 ----------------
// out[b][v] = b2[v] + sum_n relu(b1[n] + sum_sk P[sk][b][n]) * W2[n][v]
template<bool FROM_PARTIALS>
__global__ __launch_bounds__(256) void gemm2_kernel(
    const void* __restrict__ Pin, const float* __restrict__ b1,
    const float* __restrict__ W2, const float* __restrict__ b2,
    float* __restrict__ out)
{
  const int bb = blockIdx.x * 2;   // 256 blocks, 2 batch rows each
  const int v  = threadIdx.x;      // 0..255
  __shared__ float hs[2][H_];

  {
    const int id  = v * 4;
    const int row = id >> 9, col = id & 511;
    f32x4 s;
    if constexpr (FROM_PARTIALS) {
      const ushort* P = (const ushort*)Pin;
      s = *(const f32x4*)(b1 + col);
      #pragma unroll 4
      for (int sk = 0; sk < SPLITK; ++sk) {
        uint2 u = *(const uint2*)(P + (size_t)sk * (B_ * H_) + (size_t)(bb + row) * H_ + col);
        s[0] += bf2f((ushort)(u.x & 0xffff));
        s[1] += bf2f((ushort)(u.x >> 16));
        s[2] += bf2f((ushort)(u.y & 0xffff));
        s[3] += bf2f((ushort)(u.y >> 16));
      }
    } else {
      s = *(const f32x4*)((const float*)Pin + (size_t)(bb + row) * H_ + col);
    }
    f32x4 r;
    #pragma unroll
    for (int t = 0; t < 4; ++t) r[t] = fmaxf(s[t], 0.f);
    *(f32x4*)&hs[row][col] = r;
  }
  __syncthreads();

  float a0 = 0.f, a1 = 0.f;
  for (int j4 = 0; j4 < H_ / 4; ++j4) {
    f32x4 h0 = *(const f32x4*)&hs[0][j4 * 4];
    f32x4 h1 = *(const f32x4*)&hs[1][j4 * 4];
    #pragma unroll
    for (int t = 0; t < 4; ++t) {
      float w = W2[(size_t)(j4 * 4 + t) * V_ + v];
      a0 += h0[t] * w; a1 += h1[t] * w;
    }
  }
  const float bias = b2[v];
  out[(size_t)(bb + 0) * V_ + v] = a0 + bias;
  out[(size_t)(bb + 1) * V_ + v] = a1 + bias;
}

// ---------------- launch ----------------
extern "C" void kernel_launch(void* const* d_in, const int* in_sizes, int n_in,
                              void* d_out, int out_size, void* d_ws, size_t ws_size,
                              hipStream_t stream) {
  const float* x   = (const float*)d_in[0];
  const float* mem = (const float*)d_in[1];
  const int*   tim = (const int*)d_in[2];
  const float* msu = (const float*)d_in[3];
  const float* W1  = (const float*)d_in[5];
  const float* b1  = (const float*)d_in[6];
  const float* W2  = (const float*)d_in[7];
  const float* b2  = (const float*)d_in[8];
  float* out = (float*)d_out;

  char* ws = (char*)d_ws;
  const size_t abytes = (size_t)B_ * KTOT * 2;          // 35,651,584
  const size_t pbytes = (size_t)SPLITK * B_ * H_ * 2;   // 33,554,432 (bf16 partials)
  const size_t hbytes = (size_t)B_ * H_ * 4;            // 1,048,576
  const bool partials = ws_size >= abytes + pbytes + hbytes;

  ushort* A_ws  = (ushort*)ws;
  void*   P     = (void*)(ws + abytes);
  float*  h_pre = partials ? (float*)(ws + abytes + pbytes)
                           : (float*)(ws + abytes);

  prep_kernel<<<B_, 256, 0, stream>>>(x, mem, tim, msu, b1, A_ws, h_pre);
  if (partials) {
    gemm1_kernel<false><<<4 * SPLITK, 512, 0, stream>>>(A_ws, W1, P);
    gemm2_kernel<true><<<B_ / 2, 256, 0, stream>>>(P, b1, W2, b2, out);
  } else {
    gemm1_kernel<true><<<4 * SPLITK, 512, 0, stream>>>(A_ws, W1, h_pre);
    gemm2_kernel<false><<<B_ / 2, 256, 0, stream>>>(h_pre, b1, W2, b2, out);
  }
}

// Round 13
// 74.766 us; speedup vs baseline: 1.2314x; 1.0413x over previous
//
#include <hip/hip_runtime.h>

typedef unsigned int uint;
typedef unsigned short ushort;
typedef __attribute__((ext_vector_type(8))) short short8;
typedef __attribute__((ext_vector_type(4))) float f32x4;

#define B_   512
#define V_   256
#define M_   128
#define H_   512
#define T_   16
#define KTOT 34816   // V_*M_ + M_*T_

// ---------------- helpers ----------------
__device__ __forceinline__ ushort f2bf(float f) {
  uint u = __builtin_bit_cast(uint, f);
  u += 0x7fffu + ((u >> 16) & 1u);   // RNE
  return (ushort)(u >> 16);
}
__device__ __forceinline__ float bf2f(ushort s) {
  return __builtin_bit_cast(float, ((uint)s) << 16);
}

// sigma-swizzle: within each 32-element (64B) k-group, XOR the 16B-chunk index
// with ((row>>1)&3). A's writer (prep) applies it; gemm1 reads it back.
__device__ __forceinline__ int swz_k(int k, int row) {
  return (k & ~31) | (((((k >> 3) & 3) ^ ((row >> 1) & 3)) << 3)) | (k & 7);
}

// ---------------- kernel 1: per-batch prep ----------------
__global__ __launch_bounds__(256) void prep_kernel(
    const float* __restrict__ x, const float* __restrict__ mem,
    const int* __restrict__ timings, const float* __restrict__ msurp,
    const float* __restrict__ b1,
    ushort* __restrict__ A, float* __restrict__ h_pre)
{
  const int b = blockIdx.x, tid = threadIdx.x;
  __shared__ int s_t[M_];
  __shared__ int s_row[M_];
  __shared__ int s_st[M_];
  __shared__ int s_idx;

  if (tid < 64) {
    float v0 = msurp[b * M_ + tid];
    float v1 = msurp[b * M_ + tid + 64];
    float v; int i;
    if (v1 < v0) { v = v1; i = tid + 64; } else { v = v0; i = tid; }
    #pragma unroll
    for (int off = 32; off > 0; off >>= 1) {
      float ov = __shfl_down(v, off);
      int   oi = __shfl_down(i, off);
      if (ov < v || (ov == v && oi < i)) { v = ov; i = oi; }
    }
    if (tid == 0) s_idx = i;
  }
  __syncthreads();
  const int idx = s_idx;

  if (tid < M_) {
    int t = timings[b * M_ + tid] + 1;
    if (tid == idx) t = 0;
    s_t[tid] = t;
  }
  h_pre[(size_t)b * H_ + tid]       = b1[tid];
  h_pre[(size_t)b * H_ + 256 + tid] = b1[256 + tid];
  __syncthreads();

  if (tid < M_) {
    const int t = s_t[tid];
    int r = 0;
    for (int j = 0; j < M_; ++j) {
      int tj = s_t[j];
      r += (tj < t || (tj == t && j < tid)) ? 1 : 0;
    }
    s_row[r] = tid;   // order[r] = tid
    s_st[r]  = t;     // sorted_t[r]
  }
  __syncthreads();

  // bits region (k >= 32768), swizzled writes
  if (tid < M_) {
    const int t = s_st[tid];
    uint p[8];
    #pragma unroll
    for (int h = 0; h < 8; ++h) {
      uint lo = ((t >> (2 * h)) & 1) ? 0x3F80u : 0u;
      uint hi = ((t >> (2 * h + 1)) & 1) ? 0x3F80u : 0u;
      p[h] = lo | (hi << 16);
    }
    const int k0 = V_ * M_ + tid * T_;
    uint4 w0; w0.x = p[0]; w0.y = p[1]; w0.z = p[2]; w0.w = p[3];
    uint4 w1; w1.x = p[4]; w1.y = p[5]; w1.z = p[6]; w1.w = p[7];
    *(uint4*)(A + (size_t)b * KTOT + swz_k(k0, b))     = w0;
    *(uint4*)(A + (size_t)b * KTOT + swz_k(k0 + 8, b)) = w1;
  }

  // gather rows, swizzled writes (8B pieces stay within one 16B chunk)
  const int lane = tid & 63, sub = tid >> 6;
  for (int it = 0; it < 32; ++it) {
    const int slot = it * 4 + sub;
    const int rowm = s_row[slot];
    const float* src = (rowm == idx) ? (x + (size_t)b * V_)
                                     : (mem + ((size_t)b * M_ + rowm) * V_);
    f32x4 v = *(const f32x4*)(src + lane * 4);
    uint2 o;
    o.x = (uint)f2bf(v[0]) | ((uint)f2bf(v[1]) << 16);
    o.y = (uint)f2bf(v[2]) | ((uint)f2bf(v[3]) << 16);
    const int k = slot * V_ + lane * 4;
    *(uint2*)(A + (size_t)b * KTOT + swz_k(k, b)) = o;
  }
}

// ---------------- kernel 2: split-K bf16 MFMA GEMM, 512x128 tile, BK=32 ----------------
// Proven-best structure (R9/R10): depth-3 B register pipeline, 3 LDS A-buffers,
// counted vmcnt(20); never drains in steady state. At the measured ~5.8 TB/s
// issued-traffic serve ceiling (per-XCD working set > L2), 246 MB / 5.8 TB/s
// ~= 42 us = observed. Tiling is issued-byte-minimal among feasible geometries.
#define BM 512
#define BN 128
#define SPLITK 64
#define KCH 544
#define NCHU 17

#define GLD16(g, l) __builtin_amdgcn_global_load_lds( \
  (const __attribute__((address_space(1))) void*)(g), \
  (__attribute__((address_space(3))) void*)(l), 16, 0, 0)

template<bool USE_ATOMIC>
__global__ __launch_bounds__(512, 2) void gemm1_kernel(
    const ushort* __restrict__ A, const float* __restrict__ W1,
    void* __restrict__ dstv)   // fp32 h_pre (atomic) or bf16 partials P[SPLITK][512][512]
{
  __shared__ __align__(16) ushort As[3][BM * 32];   // 96 KB
  __shared__ __align__(16) ushort Bs[2][BN * 32];   // 16 KB

  const int bid  = blockIdx.x;
  // XCD-aligned: same-sk blocks share bid%8 -> same XCD (grid 256 = 4 n-tiles x 64 sk)
  const int sk   = (bid & 7) | ((bid >> 5) << 3);   // 0..63
  const int tile = (bid >> 3) & 3;                  // 4 n-tiles
  const int n0   = tile * BN;
  const int tid  = threadIdx.x, wave = tid >> 6, lane = tid & 63;
  const long kb0 = (long)sk * KCH;

  f32x4 acc[4][8];
  #pragma unroll
  for (int i = 0; i < 4; ++i)
    #pragma unroll
    for (int j = 0; j < 8; ++j) acc[i][j] = (f32x4)0.f;

  // A staging (global_load_lds, linear dest): each wave owns rows [wave*64, wave*64+64)
  const int ar  = wave * 64 + (lane >> 2);
  const int akk = (lane & 3) * 8;
  auto stageA = [&](int buf, int chunk) {
    const long kb = kb0 + (long)chunk * 32;
    #pragma unroll
    for (int q = 0; q < 4; ++q)
      GLD16(A + ((size_t)(ar + q * 16)) * KTOT + kb + akk,
            &As[buf][(wave * 64 + q * 16) * 32]);
  };

  // B staging: thread -> column n = n0+(tid&127), k-octet koct = tid>>7 (8 k's)
  const int ncol = tid & 127;
  const int koct = tid >> 7;                 // 0..3
  const float* w1p = W1 + (size_t)(kb0 + koct * 8) * H_ + n0 + ncol;
  const int b_woff = ncol * 32 + ((koct ^ ((ncol >> 1) & 3)) * 8);

  auto loadB = [&](float* r, int c) {
    const float* p = w1p + (size_t)c * 32 * H_;
    #pragma unroll
    for (int i = 0; i < 8; ++i) r[i] = p[(size_t)i * H_];
  };
  auto writeB = [&](const float* r, ushort* base) {
    uint4 o;
    o.x = (uint)f2bf(r[0]) | ((uint)f2bf(r[1]) << 16);
    o.y = (uint)f2bf(r[2]) | ((uint)f2bf(r[3]) << 16);
    o.z = (uint)f2bf(r[4]) | ((uint)f2bf(r[5]) << 16);
    o.w = (uint)f2bf(r[6]) | ((uint)f2bf(r[7]) << 16);
    *(uint4*)(base + b_woff) = o;
  };

  // de-swizzle read offset for frag loads
  const int xo     = (((lane >> 4) ^ ((lane >> 1) & 3)) * 8);
  const int a_roff = (wave * 64 + (lane & 15)) * 32;
  const int b_roff = (lane & 15) * 32;

  float brA[8], brB[8], brC[8];

// C: runtime chunk index; A3 = C%3, AS2 = (C+2)%3, CPAR = C&1 (all static);
// BRL = br[C%3] (load target, chunk C+3); BRW = br[(C+1)%3] (write source, chunk C+1)
#define GITER(C, A3, AS2, CPAR, BRL, BRW, ISSA, ISSB, WRITE, VMC) do {        \
    asm volatile("s_waitcnt vmcnt(" VMC ") lgkmcnt(0)" ::: "memory");         \
    __builtin_amdgcn_s_barrier();                                             \
    __builtin_amdgcn_sched_barrier(0);                                        \
    if (ISSA) stageA(AS2, (C) + 2);                                           \
    if (ISSB) loadB(BRL, (C) + 3);                                            \
    const ushort* as_ = &As[A3][a_roff + xo];                                 \
    const ushort* bs_ = &Bs[CPAR][b_roff + xo];                               \
    short8 af[4], bf[4];                                                      \
    _Pragma("unroll") for (int i = 0; i < 4; ++i)                             \
      af[i] = *(const short8*)(as_ + i * 16 * 32);                            \
    _Pragma("unroll") for (int j = 0; j < 4; ++j)                             \
      bf[j] = *(const short8*)(bs_ + j * 16 * 32);                            \
    _Pragma("unroll") for (int i = 0; i < 4; ++i)                             \
      _Pragma("unroll") for (int j = 0; j < 4; ++j)                           \
        acc[i][j] = __builtin_amdgcn_mfma_f32_16x16x32_bf16(af[i], bf[j],     \
                                                            acc[i][j], 0,0,0);\
    _Pragma("unroll") for (int j = 0; j < 4; ++j)                             \
      bf[j] = *(const short8*)(bs_ + (j + 4) * 16 * 32);                      \
    _Pragma("unroll") for (int i = 0; i < 4; ++i)                             \
      _Pragma("unroll") for (int j = 0; j < 4; ++j)                           \
        acc[i][j + 4] = __builtin_amdgcn_mfma_f32_16x16x32_bf16(af[i], bf[j], \
                                                            acc[i][j + 4],    \
                                                            0, 0, 0);         \
    if (WRITE) writeB(BRW, &Bs[(CPAR) ^ 1][0]);                               \
  } while (0)

  // prologue: chunks 0,1 staged (A); chunks 0,1,2 loaded (B regs); Bs[0] = chunk 0
  loadB(brA, 0);
  stageA(0, 0);
  loadB(brB, 1);
  stageA(1, 1);
  loadB(brC, 2);
  writeB(brA, &Bs[0][0]);

  #pragma unroll 1
  for (int cc = 0; cc < 12; cc += 6) {
    GITER(cc + 0, 0, 2, 0, brA, brB, true, true, true, "20");
    GITER(cc + 1, 1, 0, 1, brB, brC, true, true, true, "20");
    GITER(cc + 2, 2, 1, 0, brC, brA, true, true, true, "20");
    GITER(cc + 3, 0, 2, 1, brA, brB, true, true, true, "20");
    GITER(cc + 4, 1, 0, 0, brB, brC, true, true, true, "20");
    GITER(cc + 5, 2, 1, 1, brC, brA, true, true, true, "20");
  }
  GITER(12, 0, 2, 0, brA, brB, true,  true,  true,  "20");
  GITER(13, 1, 0, 1, brB, brC, true,  true,  true,  "20");
  GITER(14, 2, 1, 0, brC, brA, true,  false, true,  "20");
  GITER(15, 0, 2, 1, brA, brB, false, false, true,  "12");
  GITER(16, 1, 0, 0, brB, brC, false, false, false, "0");
#undef GITER

  const int row0 = wave * 64 + (lane >> 4) * 4;
  const int col0 = n0 + (lane & 15);
  if constexpr (USE_ATOMIC) {
    float* dst = (float*)dstv;
    #pragma unroll
    for (int i = 0; i < 4; ++i)
      #pragma unroll
      for (int j = 0; j < 8; ++j)
        #pragma unroll
        for (int r = 0; r < 4; ++r)
          atomicAdd(&dst[(size_t)(row0 + i * 16 + r) * H_ + col0 + j * 16], acc[i][j][r]);
  } else {
    ushort* P = (ushort*)dstv + (size_t)sk * (B_ * H_);
    #pragma unroll
    for (int i = 0; i < 4; ++i)
      #pragma unroll
      for (int j = 0; j < 8; ++j)
        #pragma unroll
        for (int r = 0; r < 4; ++r)
          P[(size_t)(row0 + i * 16 + r) * H_ + col0 + j * 16] = f2bf(acc[i][j][r]);
  }
}

// ---------------- kernel 3: fused reduce + relu + GEMM2 ----------------
// out[b][v] = b2[v] + sum_n relu(b1[n] + sum_sk P[sk][b][n]) * W2[n][v]
template<bool FROM_PARTIALS>
__global__ __launch_bounds__(256) void gemm2_kernel(
    const void* __restrict__ Pin, const float* __restrict__ b1,
    const float* __restrict__ W2, const float* __restrict__ b2,
    float* __restrict__ out)
{
  const int bb = blockIdx.x * 2;   // 256 blocks, 2 batch rows each
  const int v  = threadIdx.x;      // 0..255
  __shared__ float hs[2][H_];

  {
    const int id  = v * 4;
    const int row = id >> 9, col = id & 511;
    f32x4 s;
    if constexpr (FROM_PARTIALS) {
      const ushort* P = (const ushort*)Pin;
      s = *(const f32x4*)(b1 + col);
      #pragma unroll 4
      for (int sk = 0; sk < SPLITK; ++sk) {
        uint2 u = *(const uint2*)(P + (size_t)sk * (B_ * H_) + (size_t)(bb + row) * H_ + col);
        s[0] += bf2f((ushort)(u.x & 0xffff));
        s[1] += bf2f((ushort)(u.x >> 16));
        s[2] += bf2f((ushort)(u.y & 0xffff));
        s[3] += bf2f((ushort)(u.y >> 16));
      }
    } else {
      s = *(const f32x4*)((const float*)Pin + (size_t)(bb + row) * H_ + col);
    }
    f32x4 r;
    #pragma unroll
    for (int t = 0; t < 4; ++t) r[t] = fmaxf(s[t], 0.f);
    *(f32x4*)&hs[row][col] = r;
  }
  __syncthreads();

  float a0 = 0.f, a1 = 0.f;
  for (int j4 = 0; j4 < H_ / 4; ++j4) {
    f32x4 h0 = *(const f32x4*)&hs[0][j4 * 4];
    f32x4 h1 = *(const f32x4*)&hs[1][j4 * 4];
    #pragma unroll
    for (int t = 0; t < 4; ++t) {
      float w = W2[(size_t)(j4 * 4 + t) * V_ + v];
      a0 += h0[t] * w; a1 += h1[t] * w;
    }
  }
  const float bias = b2[v];
  out[(size_t)(bb + 0) * V_ + v] = a0 + bias;
  out[(size_t)(bb + 1) * V_ + v] = a1 + bias;
}

// ---------------- launch ----------------
extern "C" void kernel_launch(void* const* d_in, const int* in_sizes, int n_in,
                              void* d_out, int out_size, void* d_ws, size_t ws_size,
                              hipStream_t stream) {
  const float* x   = (const float*)d_in[0];
  const float* mem = (const float*)d_in[1];
  const int*   tim = (const int*)d_in[2];
  const float* msu = (const float*)d_in[3];
  const float* W1  = (const float*)d_in[5];
  const float* b1  = (const float*)d_in[6];
  const float* W2  = (const float*)d_in[7];
  const float* b2  = (const float*)d_in[8];
  float* out = (float*)d_out;

  char* ws = (char*)d_ws;
  const size_t abytes = (size_t)B_ * KTOT * 2;          // 35,651,584
  const size_t pbytes = (size_t)SPLITK * B_ * H_ * 2;   // 33,554,432 (bf16 partials)
  const size_t hbytes = (size_t)B_ * H_ * 4;            // 1,048,576
  const bool partials = ws_size >= abytes + pbytes + hbytes;

  ushort* A_ws  = (ushort*)ws;
  void*   P     = (void*)(ws + abytes);
  float*  h_pre = partials ? (float*)(ws + abytes + pbytes)
                           : (float*)(ws + abytes);

  prep_kernel<<<B_, 256, 0, stream>>>(x, mem, tim, msu, b1, A_ws, h_pre);
  if (partials) {
    gemm1_kernel<false><<<4 * SPLITK, 512, 0, stream>>>(A_ws, W1, P);
    gemm2_kernel<true><<<B_ / 2, 256, 0, stream>>>(P, b1, W2, b2, out);
  } else {
    gemm1_kernel<true><<<4 * SPLITK, 512, 0, stream>>>(A_ws, W1, h_pre);
    gemm2_kernel<false><<<B_ / 2, 256, 0, stream>>>(h_pre, b1, W2, b2, out);
  }
}